// Round 5
// baseline (300.773 us; speedup 1.0000x reference)
//
#include <hip/hip_runtime.h>

namespace {
constexpr int HW  = 1024;
constexpr int CH  = 3;
constexpr int PAD = 36;                       // padded LDS row stride (floats); 144B = 16B-aligned
constexpr int IMG_N = 8 * CH * HW * HW;       // 25165824
constexpr int PLN   = 8 * HW * HW;            // 8388608
}

__global__ __launch_bounds__(256)
void geo_perturb_kernel(const float* __restrict__ imgs,
                        const int*   __restrict__ lbls,
                        const float* __restrict__ pwin,
                        const float* __restrict__ theta,
                        float* __restrict__ out) {
    // Reference is unfused f32 numpy: round after EVERY op except the
    // deliberate FMAs below (OpenBLAS ger/trsm kernels use FMA on Zen).
    #pragma clang fp contract(off)

    __shared__ __align__(16) float simg[CH][32][PAD];
    __shared__ __align__(16) int   slbl[32][PAD];
    __shared__ __align__(16) float spw [32][PAD];

    const int blk  = blockIdx.x;          // patch index n (B, gh, gw order)
    const int bi   = blk >> 10;
    const int gy   = (blk >> 5) & 31;
    const int gx   = blk & 31;
    const int t    = threadIdx.x;
    const int row0 = gy << 5;
    const int col0 = gx << 5;

    // ---- stage patch (image float4, labels/pweight with 0 -> -1 sentinel) ----
    {
        const int r  = t >> 3;            // 0..31
        const int x4 = (t & 7) << 2;      // 0,4,...,28
#pragma unroll
        for (int c = 0; c < CH; ++c) {
            const float4 v = *reinterpret_cast<const float4*>(
                imgs + (((bi * CH + c) * HW + row0 + r) * HW + col0 + x4));
            *reinterpret_cast<float4*>(&simg[c][r][x4]) = v;
        }
        int4 lv = *reinterpret_cast<const int4*>(
            lbls + ((bi * HW + row0 + r) * HW + col0 + x4));
        lv.x = (lv.x == 0) ? -1 : lv.x;
        lv.y = (lv.y == 0) ? -1 : lv.y;
        lv.z = (lv.z == 0) ? -1 : lv.z;
        lv.w = (lv.w == 0) ? -1 : lv.w;
        *reinterpret_cast<int4*>(&slbl[r][x4]) = lv;
        float4 pv = *reinterpret_cast<const float4*>(
            pwin + ((bi * HW + row0 + r) * HW + col0 + x4));
        pv.x = (pv.x == 0.0f) ? -1.0f : pv.x;
        pv.y = (pv.y == 0.0f) ? -1.0f : pv.y;
        pv.z = (pv.z == 0.0f) ? -1.0f : pv.z;
        pv.w = (pv.w == 0.0f) ? -1.0f : pv.w;
        *reinterpret_cast<float4*>(&spw[r][x4]) = pv;
    }

    // ---- inverse affine mirroring numpy's inv == LAPACK sgesv(A, I):
    //      sgetf2 (reciprocal-scale, FMA rank-1 update) + sgetrs/strsm
    //      (pre-inverted diagonals, FMA column updates). f32 throughout. ----
    const float* th = theta + blk * 6;
    const float a = th[0], b = th[1], c0 = th[2];
    const float d = th[3], e = th[4], f0 = th[5];

    const float ra  = 1.0f / a;                      // getf2 scal reciprocal
    const float l10 = d * ra;
    const float e2  = __builtin_fmaf(l10, -b,  e);   // ger: e += l10*(-b)
    const float f2  = __builtin_fmaf(l10, -c0, f0);  // ger: f += l10*(-c)
    const float r2  = 1.0f / e2;                     // trsm pre-inverted diag
    const float i11 = r2;
    const float i10 = -l10 * r2;                     // col0: x1 = (-l10)*r2
    const float i12 = -f2  * r2;                     // col2: x1 = (-f2)*r2
    const float i00 = __builtin_fmaf(-b, i10, 1.0f) * ra;   // col0: (1 - b*x1)*ra
    const float i01 = (-b * i11) * ra;                      // col1: (0 - b*x1)*ra
    const float i02 = __builtin_fmaf(-b, i12, -c0) * ra;    // col2: (-c - b*x1)*ra

    __syncthreads();

    float*       out_img = out;
    float*       out_lbl = out + IMG_N;
    float*       out_pw  = out + IMG_N + PLN;
    const int x = t & 31;                 // lane-consecutive x -> conflict-free LDS gather

#pragma unroll
    for (int it = 0; it < 4; ++it) {
        const int y = (t >> 5) + (it << 3);          // 0..31 across iterations
        const float xf = (float)x, yf = (float)y;
        // reference tree: (ti00*xs + ti01*ys) + ti02, unfused
        const float sx = (i00 * xf + i01 * yf) + i02;
        const float sy = (i10 * xf + i11 * yf) + i12;

        // ---- bilinear (image) ----
        const float fx = floorf(sx), fy = floorf(sy);
        const float wx = sx - fx,    wy = sy - fy;
        const int x0 = (int)fx, y0 = (int)fy;
        const int x1 = x0 + 1,  y1 = y0 + 1;
        const bool bx0 = (x0 >= 0) && (x0 <= 31);
        const bool bx1 = (x1 >= 0) && (x1 <= 31);
        const bool by0 = (y0 >= 0) && (y0 <= 31);
        const bool by1 = (y1 >= 0) && (y1 <= 31);
        const float omwx = 1.0f - wx, omwy = 1.0f - wy;
        // wgt*inb: all wgts >= +0, so select(inb, wgt, +0) == wgt*inb bitwise
        const float w00 = (bx0 && by0) ? (omwx * omwy) : 0.0f;
        const float w01 = (bx1 && by0) ? (wx   * omwy) : 0.0f;
        const float w10 = (bx0 && by1) ? (omwx * wy)   : 0.0f;
        const float w11 = (bx1 && by1) ? (wx   * wy)   : 0.0f;
        const int xc0 = min(max(x0, 0), 31), yc0 = min(max(y0, 0), 31);
        const int xc1 = min(max(x1, 0), 31), yc1 = min(max(y1, 0), 31);

#pragma unroll
        for (int c = 0; c < CH; ++c) {
            // left-assoc: ((t00 + t01) + t10) + t11, each tap = v * w, unfused
            const float t00 = simg[c][yc0][xc0] * w00;
            const float t01 = simg[c][yc0][xc1] * w01;
            const float t10 = simg[c][yc1][xc0] * w10;
            const float t11 = simg[c][yc1][xc1] * w11;
            const float v = ((t00 + t01) + t10) + t11;
            const float o = (v == 0.0f) ? simg[c][y][x] : v;   // holes <- original image
            out_img[((bi * CH + c) * HW + row0 + y) * HW + col0 + x] = o;
        }

        // ---- nearest (labels + pweight); np.round == half-to-even == rintf ----
        const int xi = (int)rintf(sx);
        const int yi = (int)rintf(sy);
        const bool nin = (xi >= 0) && (xi <= 31) && (yi >= 0) && (yi <= 31);
        const int xcn = min(max(xi, 0), 31), ycn = min(max(yi, 0), 31);

        const int wl = nin ? slbl[ycn][xcn] : 0;
        int ol = (wl == 0) ? slbl[y][x] : wl;        // holes <- modified original
        ol = (ol == -1) ? 0 : ol;                    // sentinel back to 0
        out_lbl[(bi * HW + row0 + y) * HW + col0 + x] = (float)ol;

        const float wp = nin ? spw[ycn][xcn] : 0.0f;
        float op = (wp == 0.0f) ? spw[y][x] : wp;
        op = (op == -1.0f) ? 0.0f : op;
        out_pw[(bi * HW + row0 + y) * HW + col0 + x] = op;
    }
}

extern "C" void kernel_launch(void* const* d_in, const int* in_sizes, int n_in,
                              void* d_out, int out_size, void* d_ws, size_t ws_size,
                              hipStream_t stream) {
    const float* imgs  = (const float*)d_in[0];
    const int*   lbls  = (const int*)  d_in[1];
    const float* pwin  = (const float*)d_in[2];
    const float* theta = (const float*)d_in[3];
    float* out = (float*)d_out;
    (void)in_sizes; (void)n_in; (void)out_size; (void)d_ws; (void)ws_size;

    dim3 grid(8192), block(256);
    hipLaunchKernelGGL(geo_perturb_kernel, grid, block, 0, stream,
                       imgs, lbls, pwin, theta, out);
}